// Round 6
// baseline (36.022 us; speedup 1.0000x reference)
//
#include <hip/hip_runtime.h>
#include <hip/hip_bf16.h>

typedef __attribute__((ext_vector_type(8))) short bf16x8;
typedef __attribute__((ext_vector_type(4))) float f32x4;

#define N_PTS  500000
#define DIM    64
#define NCLUST 128
#define TILES  (N_PTS / 16)    // 31250, exact
#define NBLK   512             // 2 blocks/CU resident at ~200 VGPR -> 8 waves/CU
#define SSTRIDE (NBLK * 4)     // 2048 tiles per grid round
#define LOG2E  1.44269504088896f
#define LN2    0.69314718055994f

static __device__ __forceinline__ unsigned f2bf(float x) {
    union { float f; unsigned u; } un; un.f = x;
    unsigned u = un.u;
    u += 0x7fffu + ((u >> 16) & 1u);   // RNE
    return u >> 16;
}

static __device__ __forceinline__ float sq4(float4 v) {
    return v.x*v.x + v.y*v.y + v.z*v.z + v.w*v.w;
}

static __device__ __forceinline__ bf16x8 pack8(float4 a, float4 b) {
    union { bf16x8 v; __hip_bfloat162 h[4]; } u;
    u.h[0] = __float22bfloat162_rn(make_float2(a.x, a.y));
    u.h[1] = __float22bfloat162_rn(make_float2(a.z, a.w));
    u.h[2] = __float22bfloat162_rn(make_float2(b.x, b.y));
    u.h[3] = __float22bfloat162_rn(make_float2(b.z, b.w));
    return u.v;
}

static __device__ __forceinline__ float max3f(float a, float b, float c) {
    return fmaxf(fmaxf(a, b), c);   // clang fuses to v_max3_f32
}

__global__ __launch_bounds__(256) void kmeans_lse_kernel(
    const float* __restrict__ X, const float* __restrict__ centers,
    const float* __restrict__ vars_, const float* __restrict__ prs,
    const float* __restrict__ threshold, float* __restrict__ out)
{
    // Scaled centers c'_j = c_j/var_j*log2e as bf16, XOR-slot-swizzled (prologue only):
    //   element (j,k) at ushort index j*64 + (((k>>3) ^ (j&7))<<3) + (k&7)
    __shared__ unsigned short sC[NCLUST * DIM];   // 16 KB
    __shared__ float sAf[NCLUST];  // a_j = -0.5/var_j*log2e
    __shared__ float sBf[NCLUST];  // b_j = a_j*||c_j||^2 + log2(prs_j)

    const int tid = threadIdx.x;
    {   // init: 2 threads per cluster row
        const int j = tid >> 1, h = tid & 1;
        const float inv = 1.0f / vars_[j];
        const float cscale = inv * LOG2E;
        float c2p = 0.0f;
        #pragma unroll
        for (int k = 32*h; k < 32*h + 32; k += 4) {
            float4 c = *(const float4*)(centers + j*DIM + k);
            c2p = fmaf(c.x, c.x, fmaf(c.y, c.y, fmaf(c.z, c.z, fmaf(c.w, c.w, c2p))));
            const int base = j*64 + (((k >> 3) ^ (j & 7)) << 3) + (k & 7);
            sC[base+0] = (unsigned short)f2bf(c.x * cscale);
            sC[base+1] = (unsigned short)f2bf(c.y * cscale);
            sC[base+2] = (unsigned short)f2bf(c.z * cscale);
            sC[base+3] = (unsigned short)f2bf(c.w * cscale);
        }
        c2p += __shfl_xor(c2p, 1);
        if (h == 0) {
            const float a = -0.5f * inv * LOG2E;
            sAf[j] = a;
            sBf[j] = fmaf(a, c2p, __log2f(prs[j]));
        }
    }
    __syncthreads();

    const int lane = tid & 63;
    const int wid  = tid >> 6;
    const int g    = lane >> 4;   // k-chunk group (0..3)
    const int r    = lane & 15;   // point (B col) / cluster-row (A row)
    const bool g0  = (g == 0);

    // Center fragments -> registers (64 VGPRs), whole loop.
    const unsigned co1 = (unsigned)r*64 + ((unsigned)(g ^ (r & 7)) << 3);
    const unsigned co2 = co1 ^ 32;
    bf16x8 Cf0[8], Cf1[8];
    #pragma unroll
    for (int t = 0; t < 8; ++t) {
        Cf0[t] = *(const bf16x8*)&sC[t*1024 + co1];
        Cf1[t] = *(const bf16x8*)&sC[t*1024 + co2];
    }

    // Loop-invariant acc-init A-operand (32 VGPRs):
    //   k-slots [a_hi, a_hi, a_lo, b_hi, b_lo, 0,0,0] for g==0 lanes, else 0.
    // Pairs with per-iter B3 = [s_hi, s_lo, s_hi, 1, 1, 0,0,0]:
    //   sum = a_hi*s + a_lo*s_hi + b  =  a*ss + b - a_lo*s_lo (~1e-3 error).
    bf16x8 A3[8];
    #pragma unroll
    for (int t = 0; t < 8; ++t) {
        const float a = sAf[16*t + r];
        const float b = sBf[16*t + r];
        const unsigned ah = f2bf(a);
        const unsigned al = f2bf(a - __uint_as_float(ah << 16));
        const unsigned bh = f2bf(b);
        const unsigned bl = f2bf(b - __uint_as_float(bh << 16));
        union { bf16x8 v; unsigned w[4]; } u;
        u.w[0] = g0 ? (ah | (ah << 16)) : 0u;
        u.w[1] = g0 ? (al | (bh << 16)) : 0u;
        u.w[2] = g0 ? bl : 0u;
        u.w[3] = 0u;
        A3[t] = u.v;
    }

    const float thr = threshold[0];
    int tile = blockIdx.x*4 + wid;
    const size_t lane_off = (size_t)r * DIM + 8*g;

    // depth-2 double buffer, statically unrolled (no runtime buffer index)
    float4 a0, a1, a2, a3, b0, b1, b2, b3;
    {
        const float* p = X + (size_t)tile*16*DIM + lane_off;
        a0 = *(const float4*)(p);    a1 = *(const float4*)(p+4);
        a2 = *(const float4*)(p+32); a3 = *(const float4*)(p+36);
    }
    {
        const float* p = X + (size_t)(tile + SSTRIDE)*16*DIM + lane_off;  // start+2048 < 31250 always
        b0 = *(const float4*)(p);    b1 = *(const float4*)(p+4);
        b2 = *(const float4*)(p+32); b3 = *(const float4*)(p+36);
    }

    auto body = [&](float4& x0, float4& x1, float4& x2, float4& x3, int tcur) {
        // consume buffer: ss partial + bf16 pack (frees x-regs)
        float ss = sq4(x0) + sq4(x1) + sq4(x2) + sq4(x3);
        bf16x8 B0 = pack8(x0, x1);
        bf16x8 B1 = pack8(x2, x3);

        // refill same buffer with tile+2S (2-iteration load window)
        const int tp = tcur + 2*SSTRIDE;
        if (tp < TILES) {
            const float* p = X + (size_t)tp*16*DIM + lane_off;
            x0 = *(const float4*)(p);    x1 = *(const float4*)(p+4);
            x2 = *(const float4*)(p+32); x3 = *(const float4*)(p+36);
        }

        ss += __shfl_xor(ss, 16);
        ss += __shfl_xor(ss, 32);

        // B3: [s_hi, s_lo, s_hi, 1, 1, 0,0,0] on g==0 lanes
        const unsigned sh = f2bf(ss);
        const unsigned sl = f2bf(ss - __uint_as_float(sh << 16));
        union { bf16x8 v; unsigned w[4]; } ub;
        ub.w[0] = g0 ? (sh | (sl << 16)) : 0u;
        ub.w[1] = g0 ? (sh | 0x3F800000u) : 0u;   // s_hi | 1.0bf<<16
        ub.w[2] = g0 ? 0x3F80u : 0u;              // 1.0bf
        ub.w[3] = 0u;
        const bf16x8 B3 = ub.v;

        // acc[t][q] = logit~ (log2 domain) of cluster 16t+4g+q for point r
        f32x4 acc[8];
        #pragma unroll
        for (int t = 0; t < 8; ++t) {
            f32x4 z = (f32x4){0.f, 0.f, 0.f, 0.f};
            z = __builtin_amdgcn_mfma_f32_16x16x32_bf16(A3[t], B3, z, 0, 0, 0);
            z = __builtin_amdgcn_mfma_f32_16x16x32_bf16(Cf1[t], B1, z, 0, 0, 0);
            acc[t] = __builtin_amdgcn_mfma_f32_16x16x32_bf16(Cf0[t], B0, z, 0, 0, 0);
        }

        // max over 32 (4 short parallel chains, max3-fused), then 2 shuffles
        float m0 = max3f(acc[0][0], acc[1][0], acc[2][0]);
        float m1 = max3f(acc[0][1], acc[1][1], acc[2][1]);
        float m2 = max3f(acc[0][2], acc[1][2], acc[2][2]);
        float m3 = max3f(acc[0][3], acc[1][3], acc[2][3]);
        m0 = max3f(m0, acc[3][0], acc[4][0]);
        m1 = max3f(m1, acc[3][1], acc[4][1]);
        m2 = max3f(m2, acc[3][2], acc[4][2]);
        m3 = max3f(m3, acc[3][3], acc[4][3]);
        m0 = max3f(m0, acc[5][0], acc[6][0]);
        m1 = max3f(m1, acc[5][1], acc[6][1]);
        m2 = max3f(m2, acc[5][2], acc[6][2]);
        m3 = max3f(m3, acc[5][3], acc[6][3]);
        m0 = fmaxf(m0, acc[7][0]);
        m1 = fmaxf(m1, acc[7][1]);
        m2 = fmaxf(m2, acc[7][2]);
        m3 = fmaxf(m3, acc[7][3]);
        float mw = fmaxf(max3f(m0, m1, m2), m3);
        float mx = fmaxf(mw, __shfl_xor(mw, 16));
        mx = fmaxf(mx, __shfl_xor(mx, 32));

        // sum of exp2, 4 parallel chains
        float s0 = 0.f, s1 = 0.f, s2 = 0.f, s3 = 0.f;
        #pragma unroll
        for (int t = 0; t < 8; ++t) {
            s0 += __builtin_amdgcn_exp2f(acc[t][0] - mx);
            s1 += __builtin_amdgcn_exp2f(acc[t][1] - mx);
            s2 += __builtin_amdgcn_exp2f(acc[t][2] - mx);
            s3 += __builtin_amdgcn_exp2f(acc[t][3] - mx);
        }
        float sm = (s0 + s1) + (s2 + s3);
        sm += __shfl_xor(sm, 16);
        sm += __shfl_xor(sm, 32);

        if (lane < 16) {
            out[tcur*16 + lane] =
                fmaf(mx + __builtin_amdgcn_logf(sm), LN2, -thr);  // v_log_f32 = log2
        }
    };

    for (;;) {
        body(a0, a1, a2, a3, tile);
        if (tile + SSTRIDE >= TILES) break;
        body(b0, b1, b2, b3, tile + SSTRIDE);
        tile += 2*SSTRIDE;
        if (tile >= TILES) break;
    }
}

extern "C" void kernel_launch(void* const* d_in, const int* in_sizes, int n_in,
                              void* d_out, int out_size, void* d_ws, size_t ws_size,
                              hipStream_t stream) {
    const float* X         = (const float*)d_in[0];
    const float* centers   = (const float*)d_in[1];
    const float* vars_     = (const float*)d_in[2];
    const float* prs       = (const float*)d_in[3];
    const float* threshold = (const float*)d_in[4];
    float* out = (float*)d_out;
    (void)in_sizes; (void)n_in; (void)out_size; (void)d_ws; (void)ws_size;

    kmeans_lse_kernel<<<NBLK, 256, 0, stream>>>(X, centers, vars_, prs, threshold, out);
}

// Round 7
// 35.281 us; speedup vs baseline: 1.0210x; 1.0210x over previous
//
#include <hip/hip_runtime.h>
#include <hip/hip_bf16.h>

typedef __attribute__((ext_vector_type(8))) short bf16x8;
typedef __attribute__((ext_vector_type(4))) float f32x4;

#define N_PTS  500000
#define DIM    64
#define NCLUST 128
#define TILES  (N_PTS / 16)    // 31250, exact
#define NBLK   512             // 2 blocks/CU resident at ~230 VGPR -> 8 waves/CU
#define SSTRIDE (NBLK * 4)     // 2048 tiles per grid round
#define LOG2E  1.44269504088896f
#define LN2    0.69314718055994f

static __device__ __forceinline__ unsigned f2bf(float x) {
    union { float f; unsigned u; } un; un.f = x;
    unsigned u = un.u;
    u += 0x7fffu + ((u >> 16) & 1u);   // RNE
    return u >> 16;
}

static __device__ __forceinline__ float sq4(float4 v) {
    return v.x*v.x + v.y*v.y + v.z*v.z + v.w*v.w;
}

static __device__ __forceinline__ bf16x8 pack8(float4 a, float4 b) {
    union { bf16x8 v; __hip_bfloat162 h[4]; } u;
    u.h[0] = __float22bfloat162_rn(make_float2(a.x, a.y));
    u.h[1] = __float22bfloat162_rn(make_float2(a.z, a.w));
    u.h[2] = __float22bfloat162_rn(make_float2(b.x, b.y));
    u.h[3] = __float22bfloat162_rn(make_float2(b.z, b.w));
    return u.v;
}

static __device__ __forceinline__ float max3f(float a, float b, float c) {
    return fmaxf(fmaxf(a, b), c);   // clang fuses to v_max3_f32
}

__global__ __launch_bounds__(256) void kmeans_lse_kernel(
    const float* __restrict__ X, const float* __restrict__ centers,
    const float* __restrict__ vars_, const float* __restrict__ prs,
    const float* __restrict__ threshold, float* __restrict__ out)
{
    // Scaled centers c'_j = c_j/var_j*log2e as bf16, XOR-slot-swizzled (prologue only):
    //   element (j,k) at ushort index j*64 + (((k>>3) ^ (j&7))<<3) + (k&7)
    __shared__ unsigned short sC[NCLUST * DIM];   // 16 KB
    __shared__ float sAf[NCLUST];  // a_j = -0.5/var_j*log2e
    __shared__ float sBf[NCLUST];  // b_j = a_j*||c_j||^2 + log2(prs_j)

    const int tid = threadIdx.x;
    {   // init: 2 threads per cluster row
        const int j = tid >> 1, h = tid & 1;
        const float inv = 1.0f / vars_[j];
        const float cscale = inv * LOG2E;
        float c2p = 0.0f;
        #pragma unroll
        for (int k = 32*h; k < 32*h + 32; k += 4) {
            float4 c = *(const float4*)(centers + j*DIM + k);
            c2p = fmaf(c.x, c.x, fmaf(c.y, c.y, fmaf(c.z, c.z, fmaf(c.w, c.w, c2p))));
            const int base = j*64 + (((k >> 3) ^ (j & 7)) << 3) + (k & 7);
            sC[base+0] = (unsigned short)f2bf(c.x * cscale);
            sC[base+1] = (unsigned short)f2bf(c.y * cscale);
            sC[base+2] = (unsigned short)f2bf(c.z * cscale);
            sC[base+3] = (unsigned short)f2bf(c.w * cscale);
        }
        c2p += __shfl_xor(c2p, 1);
        if (h == 0) {
            const float a = -0.5f * inv * LOG2E;
            sAf[j] = a;
            sBf[j] = fmaf(a, c2p, __log2f(prs[j]));
        }
    }
    __syncthreads();

    const int lane = tid & 63;
    const int wid  = tid >> 6;
    const int g    = lane >> 4;   // k-chunk group (0..3)
    const int r    = lane & 15;   // point (B col) / cluster-row (A row)
    const bool g0  = (g == 0);

    // Center fragments -> registers (64 VGPRs), whole loop.
    const unsigned co1 = (unsigned)r*64 + ((unsigned)(g ^ (r & 7)) << 3);
    const unsigned co2 = co1 ^ 32;
    bf16x8 Cf0[8], Cf1[8];
    #pragma unroll
    for (int t = 0; t < 8; ++t) {
        Cf0[t] = *(const bf16x8*)&sC[t*1024 + co1];
        Cf1[t] = *(const bf16x8*)&sC[t*1024 + co2];
    }

    // Loop-invariant acc-init A-operand (32 VGPRs):
    //   k-slots [a_hi, a_hi, a_lo, b_hi, b_lo, 0,0,0] for g==0 lanes, else 0.
    // Pairs with per-iter B3 = [s_hi, s_lo, s_hi, 1, 1, 0,0,0]:
    //   sum = a_hi*s + a_lo*s_hi + b  =  a*ss + b - a_lo*s_lo (~1e-3 error).
    bf16x8 A3[8];
    #pragma unroll
    for (int t = 0; t < 8; ++t) {
        const float a = sAf[16*t + r];
        const float b = sBf[16*t + r];
        const unsigned ah = f2bf(a);
        const unsigned al = f2bf(a - __uint_as_float(ah << 16));
        const unsigned bh = f2bf(b);
        const unsigned bl = f2bf(b - __uint_as_float(bh << 16));
        union { bf16x8 v; unsigned w[4]; } u;
        u.w[0] = g0 ? (ah | (ah << 16)) : 0u;
        u.w[1] = g0 ? (al | (bh << 16)) : 0u;
        u.w[2] = g0 ? bl : 0u;
        u.w[3] = 0u;
        A3[t] = u.v;
    }

    const float thr = threshold[0];
    int tile = blockIdx.x*4 + wid;
    const size_t lane_off = (size_t)r * DIM + 8*g;

    // depth-3 ring of register buffers, statically unrolled (no runtime index)
    float4 a0, a1, a2, a3, b0, b1, b2, b3, c0, c1, c2, c3;
    {
        const float* p = X + (size_t)tile*16*DIM + lane_off;
        a0 = *(const float4*)(p);    a1 = *(const float4*)(p+4);
        a2 = *(const float4*)(p+32); a3 = *(const float4*)(p+36);
    }
    {
        const float* p = X + (size_t)(tile + SSTRIDE)*16*DIM + lane_off;   // max 2047+2048 < 31250
        b0 = *(const float4*)(p);    b1 = *(const float4*)(p+4);
        b2 = *(const float4*)(p+32); b3 = *(const float4*)(p+36);
    }
    {
        const float* p = X + (size_t)(tile + 2*SSTRIDE)*16*DIM + lane_off; // max 2047+4096 < 31250
        c0 = *(const float4*)(p);    c1 = *(const float4*)(p+4);
        c2 = *(const float4*)(p+32); c3 = *(const float4*)(p+36);
    }

    auto body = [&](float4& x0, float4& x1, float4& x2, float4& x3, int tcur) {
        // consume buffer: ss partial + bf16 pack (frees x-regs)
        float ss = sq4(x0) + sq4(x1) + sq4(x2) + sq4(x3);
        bf16x8 B0 = pack8(x0, x1);
        bf16x8 B1 = pack8(x2, x3);

        // refill same buffer with tile+3S (3-iteration load window)
        const int tp = tcur + 3*SSTRIDE;
        if (tp < TILES) {
            const float* p = X + (size_t)tp*16*DIM + lane_off;
            x0 = *(const float4*)(p);    x1 = *(const float4*)(p+4);
            x2 = *(const float4*)(p+32); x3 = *(const float4*)(p+36);
        }

        ss += __shfl_xor(ss, 16);
        ss += __shfl_xor(ss, 32);

        // B3: [s_hi, s_lo, s_hi, 1, 1, 0,0,0] on g==0 lanes
        const unsigned sh = f2bf(ss);
        const unsigned sl = f2bf(ss - __uint_as_float(sh << 16));
        union { bf16x8 v; unsigned w[4]; } ub;
        ub.w[0] = g0 ? (sh | (sl << 16)) : 0u;
        ub.w[1] = g0 ? (sh | 0x3F800000u) : 0u;   // s_hi | 1.0bf<<16
        ub.w[2] = g0 ? 0x3F80u : 0u;              // 1.0bf
        ub.w[3] = 0u;
        const bf16x8 B3 = ub.v;

        // acc[t][q] = logit~ (log2 domain) of cluster 16t+4g+q for point r
        f32x4 acc[8];
        #pragma unroll
        for (int t = 0; t < 8; ++t) {
            f32x4 z = (f32x4){0.f, 0.f, 0.f, 0.f};
            z = __builtin_amdgcn_mfma_f32_16x16x32_bf16(A3[t], B3, z, 0, 0, 0);
            z = __builtin_amdgcn_mfma_f32_16x16x32_bf16(Cf1[t], B1, z, 0, 0, 0);
            acc[t] = __builtin_amdgcn_mfma_f32_16x16x32_bf16(Cf0[t], B0, z, 0, 0, 0);
        }

        // max over 32 (4 short parallel chains, max3-fused), then 2 shuffles
        float m0 = max3f(acc[0][0], acc[1][0], acc[2][0]);
        float m1 = max3f(acc[0][1], acc[1][1], acc[2][1]);
        float m2 = max3f(acc[0][2], acc[1][2], acc[2][2]);
        float m3 = max3f(acc[0][3], acc[1][3], acc[2][3]);
        m0 = max3f(m0, acc[3][0], acc[4][0]);
        m1 = max3f(m1, acc[3][1], acc[4][1]);
        m2 = max3f(m2, acc[3][2], acc[4][2]);
        m3 = max3f(m3, acc[3][3], acc[4][3]);
        m0 = max3f(m0, acc[5][0], acc[6][0]);
        m1 = max3f(m1, acc[5][1], acc[6][1]);
        m2 = max3f(m2, acc[5][2], acc[6][2]);
        m3 = max3f(m3, acc[5][3], acc[6][3]);
        m0 = fmaxf(m0, acc[7][0]);
        m1 = fmaxf(m1, acc[7][1]);
        m2 = fmaxf(m2, acc[7][2]);
        m3 = fmaxf(m3, acc[7][3]);
        float mw = fmaxf(max3f(m0, m1, m2), m3);
        float mx = fmaxf(mw, __shfl_xor(mw, 16));
        mx = fmaxf(mx, __shfl_xor(mx, 32));

        // sum of exp2, 4 parallel chains
        float s0 = 0.f, s1 = 0.f, s2 = 0.f, s3 = 0.f;
        #pragma unroll
        for (int t = 0; t < 8; ++t) {
            s0 += __builtin_amdgcn_exp2f(acc[t][0] - mx);
            s1 += __builtin_amdgcn_exp2f(acc[t][1] - mx);
            s2 += __builtin_amdgcn_exp2f(acc[t][2] - mx);
            s3 += __builtin_amdgcn_exp2f(acc[t][3] - mx);
        }
        float sm = (s0 + s1) + (s2 + s3);
        sm += __shfl_xor(sm, 16);
        sm += __shfl_xor(sm, 32);

        if (lane < 16) {
            out[tcur*16 + lane] =
                fmaf(mx + __builtin_amdgcn_logf(sm), LN2, -thr);  // v_log_f32 = log2
        }
    };

    for (;;) {
        body(a0, a1, a2, a3, tile);
        if (tile + SSTRIDE >= TILES) break;
        body(b0, b1, b2, b3, tile + SSTRIDE);
        if (tile + 2*SSTRIDE >= TILES) break;
        body(c0, c1, c2, c3, tile + 2*SSTRIDE);
        tile += 3*SSTRIDE;
        if (tile >= TILES) break;
    }
}

extern "C" void kernel_launch(void* const* d_in, const int* in_sizes, int n_in,
                              void* d_out, int out_size, void* d_ws, size_t ws_size,
                              hipStream_t stream) {
    const float* X         = (const float*)d_in[0];
    const float* centers   = (const float*)d_in[1];
    const float* vars_     = (const float*)d_in[2];
    const float* prs       = (const float*)d_in[3];
    const float* threshold = (const float*)d_in[4];
    float* out = (float*)d_out;
    (void)in_sizes; (void)n_in; (void)out_size; (void)d_ws; (void)ws_size;

    kmeans_lse_kernel<<<NBLK, 256, 0, stream>>>(X, centers, vars_, prs, threshold, out);
}